// Round 6
// baseline (308.573 us; speedup 1.0000x reference)
//
#include <hip/hip_runtime.h>
#include <hip/hip_fp16.h>

// InteractionBlock, MI355X, round 6: slot-major slice-aligned gather.
//
// y = out @ W3 + gathersum(out) @ (W2@W3) + (b2@W3 + b3)
// R5 post-mortem: slice-phasing cut FETCH 153->59.5 MB but the scalar
// pair-extraction loop was latency-bound (2 loads in flight/wave, 770 GB/s).
// R6 keeps the locality, fixes the MLP: indices are sorted per-g by address
// slice (idx>>12); the gather loop is slot-major (k outer, 16 g's inner,
// fully unrolled) -> 16 independent loads in flight per wave, and since slot
// k ~ address quantile k/32 (+-1 MB binomial jitter), all co-resident blocks
// sweep the same few-MB window together -> per-XCD L2 stays hot. Grid = 782
// blocks = ONE generation at 4 blocks/CU (LDS 34.8 KB, VGPR<=128), so blocks
// stay in lockstep. Epilogue: mfma_f32_16x16x32_f16, 8 row-tiles (2/wave),
// B-frags straight from the 16 KB global WTg (cache-resident).
// Prep (pack fp16 rows / per-g sort / W23 precompute) merged into ONE kernel.

constexpr int A   = 64;    // ao_vals
constexpr int K   = 32;    // neighbors
constexpr int GPW = 16;    // grid points per wave
constexpr int GPB = 64;    // grid points per block (4 waves)
constexpr int XS  = 136;   // X row stride in halves (16B rows + 4-bank shift)
constexpr int NSLICE = 13; // idx>>12; G+1=50001 -> slices 0..12

typedef _Float16 f16x8 __attribute__((ext_vector_type(8)));
typedef float    f32x4 __attribute__((ext_vector_type(4)));

// ---- prep kernel: three independent roles in one launch ----
// role 1 (all blocks): pack out (fp32 [2][G][64]) -> packed ([G+1][64] half2),
//   row G = materialized zero row. dword c of row g: c<32 -> batch0 pair
//   (2c,2c+1), else batch1.
// role 2 (blocks with g<G): counting-sort g's 32 indices by slice (idx>>12),
//   stable within slice, write sorted[g][32].
// role 3 (last block): WTg[n][0..127] = (half) concat(W2@W3, W3) column n;
//   bb = b2@W3 + b3 (fp32).
__global__ void prep_kernel(const float2* __restrict__ out2,
                            const int* __restrict__ nbr,
                            const float* __restrict__ W2, const float* __restrict__ b2,
                            const float* __restrict__ W3, const float* __restrict__ b3,
                            __half2* __restrict__ packed, int* __restrict__ sorted,
                            __half* __restrict__ WTg, float* __restrict__ bb,
                            const int G, const int nBlocks) {
  const int tid = threadIdx.x;
  const int d = blockIdx.x * 256 + tid;

  // role 1: pack
  if (d < (G + 1) * 64) {
    const int g = d >> 6, c = d & 63;
    float2 v = make_float2(0.f, 0.f);
    if (g < G) v = out2[(size_t)(c >> 5) * (G * 32) + (size_t)g * 32 + (c & 31)];
    packed[d] = __floats2half2_rn(v.x, v.y);
  }

  // role 2: per-g slice sort (thread d handles g = d)
  if (d < G) {
    int v[K];
#pragma unroll
    for (int k = 0; k < K; ++k) v[k] = nbr[d * K + k];
    int* dst = sorted + (size_t)d * K;
    int pos = 0;
#pragma unroll
    for (int s = 0; s < NSLICE; ++s)
#pragma unroll
      for (int k = 0; k < K; ++k)
        if ((v[k] >> 12) == s) dst[pos++] = v[k];
  }

  // role 3: weight prep (last block only; covers all 4096 elements)
  if (blockIdx.x == nBlocks - 1) {
#pragma unroll 1
    for (int e = tid; e < A * A; e += 256) {
      const int n = e >> 6, k = e & 63;
      float acc = 0.f;
#pragma unroll
      for (int q = 0; q < A; ++q) acc = fmaf(W2[k * A + q], W3[q * A + n], acc);
      WTg[n * 128 + k]     = __float2half(acc);            // W23 (k = 0..63)
      WTg[n * 128 + A + k] = __float2half(W3[k * A + n]);  // W3  (k = 64..127)
    }
    if (tid < A) {
      float b = b3[tid];
#pragma unroll
      for (int q = 0; q < A; ++q) b = fmaf(b2[q], W3[q * A + tid], b);
      bb[tid] = b;
    }
  }
}

// ---- fused kernel: slot-major gather + MFMA epilogue ----
// LDS: X = 128 x 136 halves = 34.8 KB -> 4 blocks/CU; grid 782 <= 1024 ->
// one co-resident generation, lockstep slot sweep.
__global__ __launch_bounds__(256, 4) void fused_kernel(
    const __half2* __restrict__ packed, const int* __restrict__ sorted,
    const __half* __restrict__ WTg, const float* __restrict__ bb,
    float* __restrict__ y, const int G) {
  __shared__ __half X[128 * XS];   // row = batch*64 + gl; cols [m(64)|o(64)]

  const int tid = threadIdx.x;
  const int lane = tid & 63;
  const int w = tid >> 6;
  const int g0 = blockIdx.x * GPB + w * GPW;   // this wave's first g

  // Preload sorted index vectors: lane j (mod 32) holds slot j of each g.
  int idxv[GPW];
  __half2 acc[GPW];
  const __half2 z = __floats2half2_rn(0.f, 0.f);
#pragma unroll
  for (int gi = 0; gi < GPW; ++gi) {
    const int g = g0 + gi;
    idxv[gi] = (g < G) ? sorted[(size_t)g * K + (lane & 31)] : G;
    acc[gi] = z;
  }

  // Slot-major gather: at step k every wave machine-wide reads rows near
  // address quantile k/32 -> per-XCD working set ~2-3 MB, L2-resident.
  // 16 independent chains -> 16+ loads in flight per wave.
#pragma unroll 4
  for (int k = 0; k < K; ++k) {
#pragma unroll
    for (int gi = 0; gi < GPW; ++gi) {
      const int j = __builtin_amdgcn_readlane(idxv[gi], k);  // uniform -> SGPR
      acc[gi] = __hadd2(acc[gi], packed[(size_t)j * 64 + lane]);
    }
  }

  // Stage X: message (cols 0..63) + residual row (cols 64..127).
  const int e2 = 2 * (lane & 31);
  const int rb = (lane >> 5) * 64;             // batch row base
#pragma unroll
  for (int gi = 0; gi < GPW; ++gi) {
    const int g = g0 + gi;
    const int row = rb + w * GPW + gi;
    *(__half2*)&X[row * XS + e2] = acc[gi];
    const __half2 o = (g < G) ? packed[(size_t)g * 64 + lane] : z;
    *(__half2*)&X[row * XS + A + e2] = o;
  }
  __syncthreads();

  // Epilogue: Y[128x64] = X[128x128] @ Wcat; tiles t = w and w+4.
  // A-frag A[m=lane&15][k=quad*8+j]; B-frag B[k=quad*8+j][n=lane&15];
  // C/D: col=lane&15, row=quad*4+reg.
  const int quad = lane >> 4, mn = lane & 15;
#pragma unroll
  for (int jt = 0; jt < 2; ++jt) {
    const int t = w + 4 * jt;
    f32x4 ac[4] = {{0.f, 0.f, 0.f, 0.f}, {0.f, 0.f, 0.f, 0.f},
                   {0.f, 0.f, 0.f, 0.f}, {0.f, 0.f, 0.f, 0.f}};
#pragma unroll
    for (int kt = 0; kt < 4; ++kt) {
      const int ko = kt * 32 + quad * 8;
      const f16x8 a = *(const f16x8*)&X[(t * 16 + mn) * XS + ko];
#pragma unroll
      for (int nt = 0; nt < 4; ++nt) {
        const f16x8 bfr = *(const f16x8*)&WTg[(nt * 16 + mn) * 128 + ko];
        ac[nt] = __builtin_amdgcn_mfma_f32_16x16x32_f16(a, bfr, ac[nt], 0, 0, 0);
      }
    }
#pragma unroll
    for (int nt = 0; nt < 4; ++nt) {
      const int col = nt * 16 + mn;
      const float bv = bb[col];
#pragma unroll
      for (int rg = 0; rg < 4; ++rg) {
        const int r = quad * 4 + rg;               // row within tile
        const int bt = t >> 2;                     // batch
        const int g = blockIdx.x * GPB + (t & 3) * 16 + r;
        if (g < G) y[((size_t)bt * G + g) * 64 + col] = ac[nt][rg] + bv;
      }
    }
  }
}

extern "C" void kernel_launch(void* const* d_in, const int* in_sizes, int n_in,
                              void* d_out, int out_size, void* d_ws, size_t ws_size,
                              hipStream_t stream) {
  const float* out = (const float*)d_in[0];
  const int*   nbr = (const int*)d_in[1];
  const float* W2  = (const float*)d_in[2];
  const float* b2  = (const float*)d_in[3];
  const float* W3  = (const float*)d_in[4];
  const float* b3  = (const float*)d_in[5];
  float* y = (float*)d_out;
  const int G = in_sizes[1] / K;

  // ws: packed (G+1)*64 half2 | sorted G*32 int | WTg 128*64 half | bb 64 f32
  __half2* packed = (__half2*)d_ws;
  const size_t pbytes = (size_t)(G + 1) * 64 * sizeof(__half2);
  int* sorted = (int*)((char*)d_ws + pbytes);
  __half* WTg = (__half*)((char*)sorted + (size_t)G * K * sizeof(int));
  float* bbp = (float*)(WTg + 128 * 64);

  const int nPrep = ((G + 1) * 64 + 255) / 256;
  prep_kernel<<<nPrep, 256, 0, stream>>>((const float2*)out, nbr, W2, b2, W3, b3,
                                         packed, sorted, WTg, bbp, G, nPrep);

  const int blocks = (G + GPB - 1) / GPB;
  fused_kernel<<<blocks, 256, 0, stream>>>(packed, sorted, WTg, bbp, y, G);
}

// Round 7
// 225.722 us; speedup vs baseline: 1.3670x; 1.3670x over previous
//
#include <hip/hip_runtime.h>
#include <hip/hip_fp16.h>

// InteractionBlock, MI355X, round 7: slot-major gather, SMEM-sourced indices.
//
// y = out @ W3 + gathersum(out) @ (W2@W3) + (b2@W3 + b3)
// R4 taught: s_load-sourced uniform indices -> 4+ loads in flight/wave, EA
// path saturated (3.25 TB/s). R5/R6 taught: machine-aligned slot-major sweep
// over per-g sorted indices -> FETCH 153->60 MB; but readlane-sourced
// addresses serialized (MLP~1, 770->670 GB/s). R7 combines both:
//   prep: per-g FULL value sort (per-wave 32-step rank loop), stored
//         TRANSPOSED: sortedT[rank][g] (rank-major rows, Gpad columns).
//   fused: wave owns 16 consecutive g's; slot k reads sortedT[k][g0w..+15]
//         as ONE s_load_dwordx16 (wave-uniform contiguous), then 16
//         independent global row loads into 16 fp16 acc chains. k sweeps
//         0..31 machine-wide -> all co-resident blocks read the same
//         address quantile window -> per-XCD L2 stays hot.
// Epilogue: mfma_f32_16x16x32_f16 as R4/R6 (verified mapping). 2 launches.

constexpr int A   = 64;    // ao_vals
constexpr int K   = 32;    // neighbors
constexpr int GPW = 16;    // grid points per wave
constexpr int GPB = 64;    // grid points per block (4 waves)
constexpr int XS  = 136;   // X row stride in halves (16B rows, 4-bank shift)

typedef _Float16 f16x8 __attribute__((ext_vector_type(8)));
typedef float    f32x4 __attribute__((ext_vector_type(4)));

// ---- prep kernel: pack + per-wave rank-sort + weight prep, one launch ----
// role 1 (per thread d): pack out (fp32 [2][G][64]) -> packed ([G+1][64]
//   half2); dword c of row g: c<32 -> batch0 pair (2c,2c+1), else batch1;
//   row G = materialized zero row.
// role 2 (per wave, g = global wave id): rank = #{j: v_j < v_me or tie,j<me}
//   over the 32 indices (full value sort; sum is order-invariant), write
//   sortedT[rank*Gpad + g]. 32 readlane+cmp steps, no LDS, no branches.
// role 3 (last block): WTg[n][0..127] = (half) concat(W2@W3, W3) col n;
//   bb = b2@W3 + b3 (fp32).
__global__ void prep_kernel(const float2* __restrict__ out2,
                            const int* __restrict__ nbr,
                            const float* __restrict__ W2, const float* __restrict__ b2,
                            const float* __restrict__ W3, const float* __restrict__ b3,
                            __half2* __restrict__ packed, int* __restrict__ sortedT,
                            __half* __restrict__ WTg, float* __restrict__ bb,
                            const int G, const int Gpad, const int nBlocks) {
  const int tid = threadIdx.x;
  const int d = blockIdx.x * 256 + tid;

  // role 1: pack
  if (d < (G + 1) * 64) {
    const int g = d >> 6, c = d & 63;
    float2 v = make_float2(0.f, 0.f);
    if (g < G) v = out2[(size_t)(c >> 5) * (G * 32) + (size_t)g * 32 + (c & 31)];
    packed[d] = __floats2half2_rn(v.x, v.y);
  }

  // role 2: per-wave value-rank sort (wave g = blockIdx*4 + waveId)
  {
    const int lane = tid & 63;
    const int g = blockIdx.x * 4 + (tid >> 6);
    if (g < G) {
      const int myv = (lane < K) ? nbr[(size_t)g * K + lane] : 0x7FFFFFFF;
      int rank = 0;
#pragma unroll
      for (int j = 0; j < K; ++j) {
        const int vj = __builtin_amdgcn_readlane(myv, j);
        rank += ((vj < myv) || (vj == myv && j < lane)) ? 1 : 0;
      }
      if (lane < K) sortedT[(size_t)rank * Gpad + g] = myv;
    }
  }

  // role 3: weight prep (last block)
  if (blockIdx.x == nBlocks - 1) {
#pragma unroll 1
    for (int e = tid; e < A * A; e += 256) {
      const int n = e >> 6, k = e & 63;
      float acc = 0.f;
#pragma unroll
      for (int q = 0; q < A; ++q) acc = fmaf(W2[k * A + q], W3[q * A + n], acc);
      WTg[n * 128 + k]     = __float2half(acc);            // W23 (k = 0..63)
      WTg[n * 128 + A + k] = __float2half(W3[k * A + n]);  // W3  (k = 64..127)
    }
    if (tid < A) {
      float b = b3[tid];
#pragma unroll
      for (int q = 0; q < A; ++q) b = fmaf(b2[q], W3[q * A + tid], b);
      bb[tid] = b;
    }
  }
}

// ---- fused kernel: slot-major SMEM-indexed gather + MFMA epilogue ----
// LDS X = 128 x 136 halves = 34.8 KB -> 4 blocks/CU; grid 782 -> one
// co-resident generation (<=1024), near-lockstep k sweep.
__global__ __launch_bounds__(256, 4) void fused_kernel(
    const __half2* __restrict__ packed, const int* __restrict__ sortedT,
    const __half* __restrict__ WTg, const float* __restrict__ bb,
    float* __restrict__ y, const int G, const int Gpad) {
  __shared__ __half X[128 * XS];   // row = batch*64 + gl; cols [m(64)|o(64)]

  const int tid = threadIdx.x;
  const int lane = tid & 63;
  const int w = __builtin_amdgcn_readfirstlane(tid >> 6);  // uniform wave id
  const int g0w = blockIdx.x * GPB + w * GPW;              // wave's first g

  const __half2 z = __floats2half2_rn(0.f, 0.f);
  __half2 acc[GPW];
#pragma unroll
  for (int gi = 0; gi < GPW; ++gi) acc[gi] = z;

  // G % GPW == 0, so each wave's 16 g's are all-valid or all-invalid.
  if (g0w < G) {
    // Slot-major gather. ip is wave-uniform + contiguous -> s_load_dwordx16;
    // 16 independent loads in flight per slot, 16 fp16 acc chains.
#pragma unroll 2
    for (int k = 0; k < K; ++k) {
      const int* ip = sortedT + (size_t)k * Gpad + g0w;    // uniform pointer
#pragma unroll
      for (int gi = 0; gi < GPW; ++gi) {
        const int j = ip[gi];                              // SGPR via s_load
        acc[gi] = __hadd2(acc[gi], packed[(size_t)j * 64 + lane]);
      }
    }

    // Stage X: message (cols 0..63) + residual row (cols 64..127).
    const int e2 = 2 * (lane & 31);
    const int rb = (lane >> 5) * 64;                       // batch row base
#pragma unroll
    for (int gi = 0; gi < GPW; ++gi) {
      const int row = rb + w * GPW + gi;
      *(__half2*)&X[row * XS + e2] = acc[gi];
      *(__half2*)&X[row * XS + A + e2] = packed[(size_t)(g0w + gi) * 64 + lane];
    }
  }
  __syncthreads();

  // Epilogue: Y[128x64] = X[128x128] @ Wcat; tiles t = w and w+4.
  // A-frag A[m=lane&15][k=quad*8+j]; B-frag B[k=quad*8+j][n=lane&15];
  // C/D: col=lane&15, row=quad*4+reg. (Verified in R4/R6.)
  const int quad = lane >> 4, mn = lane & 15;
#pragma unroll
  for (int jt = 0; jt < 2; ++jt) {
    const int t = w + 4 * jt;
    f32x4 ac[4] = {{0.f, 0.f, 0.f, 0.f}, {0.f, 0.f, 0.f, 0.f},
                   {0.f, 0.f, 0.f, 0.f}, {0.f, 0.f, 0.f, 0.f}};
#pragma unroll
    for (int kt = 0; kt < 4; ++kt) {
      const int ko = kt * 32 + quad * 8;
      const f16x8 a = *(const f16x8*)&X[(t * 16 + mn) * XS + ko];
#pragma unroll
      for (int nt = 0; nt < 4; ++nt) {
        const f16x8 bfr = *(const f16x8*)&WTg[(nt * 16 + mn) * 128 + ko];
        ac[nt] = __builtin_amdgcn_mfma_f32_16x16x32_f16(a, bfr, ac[nt], 0, 0, 0);
      }
    }
#pragma unroll
    for (int nt = 0; nt < 4; ++nt) {
      const int col = nt * 16 + mn;
      const float bv = bb[col];
#pragma unroll
      for (int rg = 0; rg < 4; ++rg) {
        const int r = quad * 4 + rg;               // row within tile
        const int bt = t >> 2;                     // batch
        const int g = blockIdx.x * GPB + (t & 3) * 16 + r;
        if (g < G) y[((size_t)bt * G + g) * 64 + col] = ac[nt][rg] + bv;
      }
    }
  }
}

extern "C" void kernel_launch(void* const* d_in, const int* in_sizes, int n_in,
                              void* d_out, int out_size, void* d_ws, size_t ws_size,
                              hipStream_t stream) {
  const float* out = (const float*)d_in[0];
  const int*   nbr = (const int*)d_in[1];
  const float* W2  = (const float*)d_in[2];
  const float* b2  = (const float*)d_in[3];
  const float* W3  = (const float*)d_in[4];
  const float* b3  = (const float*)d_in[5];
  float* y = (float*)d_out;
  const int G = in_sizes[1] / K;
  const int Gpad = (G + 63) & ~63;   // 64-aligned rows for aligned s_loads

  // ws: packed (G+1)*64 half2 | sortedT K*Gpad int | WTg 128*64 half | bb 64 f32
  __half2* packed = (__half2*)d_ws;
  const size_t pbytes = (size_t)(G + 1) * 64 * sizeof(__half2);
  int* sortedT = (int*)((char*)d_ws + pbytes);
  __half* WTg = (__half*)((char*)sortedT + (size_t)K * Gpad * sizeof(int));
  float* bbp = (float*)(WTg + 128 * 64);

  const int nPrep = ((G + 1) * 64 + 255) / 256;
  prep_kernel<<<nPrep, 256, 0, stream>>>((const float2*)out, nbr, W2, b2, W3, b3,
                                         packed, sortedT, WTg, bbp, G, Gpad, nPrep);

  const int blocks = (G + GPB - 1) / GPB;
  fused_kernel<<<blocks, 256, 0, stream>>>(packed, sortedT, WTg, bbp, y, G, Gpad);
}

// Round 8
// 217.915 us; speedup vs baseline: 1.4160x; 1.0358x over previous
//
#include <hip/hip_runtime.h>
#include <hip/hip_fp16.h>

// InteractionBlock, MI355X, round 8.
//
// y = out @ W3 + gathersum(out) @ (W2@W3) + (b2@W3 + b3)
// R7 post-mortem: fused slot-major gather with SMEM-sourced transposed
// indices works (fused fell out of the top-5, < ~45us); prep became the
// bottleneck (124-134us) because the per-wave rank-sort scattered single
// dwords with 200KB stride (32 lines per store). R8 keeps fused bit-for-bit
// and fixes prep: per-THREAD bitonic sorting network (32 ints in registers,
// 240 static compare-exchanges, no scratch), then transposed writes done
// COALESCED: at rank k, a block's 256 threads write 256 consecutive dwords
// of row k. prep -> memory-bound (~77MB moved, ~15-20us).

constexpr int A   = 64;    // ao_vals
constexpr int K   = 32;    // neighbors
constexpr int GPW = 16;    // grid points per wave
constexpr int GPB = 64;    // grid points per block (4 waves)
constexpr int XS  = 136;   // X row stride in halves (16B rows, 4-bank shift)

typedef _Float16 f16x8 __attribute__((ext_vector_type(8)));
typedef float    f32x4 __attribute__((ext_vector_type(4)));

// ---- prep kernel ----
// role 1 (thread d): pack out (fp32 [2][G][64]) -> packed ([G+1][64] half2);
//   dword c of row g: c<32 -> batch0 pair (2c,2c+1), else batch1; row G = 0.
// role 2 (thread d = g < G): bitonic-sort g's 32 neighbor indices ascending
//   in registers; write transposed sortedT[k*Gpad + g] (coalesced per rank).
// role 3 (last block): WTg[n][0..127] = (half) concat(W2@W3, W3) col n;
//   bb = b2@W3 + b3 (fp32).
__global__ void prep_kernel(const float2* __restrict__ out2,
                            const int* __restrict__ nbr,
                            const float* __restrict__ W2, const float* __restrict__ b2,
                            const float* __restrict__ W3, const float* __restrict__ b3,
                            __half2* __restrict__ packed, int* __restrict__ sortedT,
                            __half* __restrict__ WTg, float* __restrict__ bb,
                            const int G, const int Gpad, const int nBlocks) {
  const int tid = threadIdx.x;
  const int d = blockIdx.x * 256 + tid;

  // role 1: pack
  if (d < (G + 1) * 64) {
    const int g = d >> 6, c = d & 63;
    float2 v = make_float2(0.f, 0.f);
    if (g < G) v = out2[(size_t)(c >> 5) * (G * 32) + (size_t)g * 32 + (c & 31)];
    packed[d] = __floats2half2_rn(v.x, v.y);
  }

  // role 2: per-thread bitonic sort + coalesced transposed write
  if (d < G) {
    int v[K];
    const int4* np = (const int4*)(nbr + (size_t)d * K);   // 128B/thread
#pragma unroll
    for (int q = 0; q < 8; ++q) {
      const int4 t4 = np[q];
      v[4 * q] = t4.x; v[4 * q + 1] = t4.y; v[4 * q + 2] = t4.z; v[4 * q + 3] = t4.w;
    }
    // Bitonic network, ascending; all indices static -> registers only.
#pragma unroll
    for (int sz = 2; sz <= K; sz <<= 1) {
#pragma unroll
      for (int st = sz >> 1; st >= 1; st >>= 1) {
#pragma unroll
        for (int i = 0; i < K; ++i) {
          const int j = i ^ st;
          if (j > i) {
            const bool up = (i & sz) == 0;
            const int a = v[i], b = v[j];
            const int lo = a < b ? a : b, hi = a < b ? b : a;
            v[i] = up ? lo : hi;
            v[j] = up ? hi : lo;
          }
        }
      }
    }
#pragma unroll
    for (int k = 0; k < K; ++k)
      sortedT[(size_t)k * Gpad + d] = v[k];   // 256 consecutive dwords/block
  }

  // role 3: weight prep (last block)
  if (blockIdx.x == nBlocks - 1) {
#pragma unroll 1
    for (int e = tid; e < A * A; e += 256) {
      const int n = e >> 6, k = e & 63;
      float acc = 0.f;
#pragma unroll
      for (int q = 0; q < A; ++q) acc = fmaf(W2[k * A + q], W3[q * A + n], acc);
      WTg[n * 128 + k]     = __float2half(acc);            // W23 (k = 0..63)
      WTg[n * 128 + A + k] = __float2half(W3[k * A + n]);  // W3  (k = 64..127)
    }
    if (tid < A) {
      float b = b3[tid];
#pragma unroll
      for (int q = 0; q < A; ++q) b = fmaf(b2[q], W3[q * A + tid], b);
      bb[tid] = b;
    }
  }
}

// ---- fused kernel: slot-major SMEM-indexed gather + MFMA epilogue ----
// (unchanged from R7 -- it fell out of the top-5 there)
// LDS X = 128 x 136 halves = 34.8 KB -> 4 blocks/CU; grid 782 -> one
// co-resident generation, near-lockstep k sweep over address quantiles.
__global__ __launch_bounds__(256, 4) void fused_kernel(
    const __half2* __restrict__ packed, const int* __restrict__ sortedT,
    const __half* __restrict__ WTg, const float* __restrict__ bb,
    float* __restrict__ y, const int G, const int Gpad) {
  __shared__ __half X[128 * XS];   // row = batch*64 + gl; cols [m(64)|o(64)]

  const int tid = threadIdx.x;
  const int lane = tid & 63;
  const int w = __builtin_amdgcn_readfirstlane(tid >> 6);  // uniform wave id
  const int g0w = blockIdx.x * GPB + w * GPW;              // wave's first g

  const __half2 z = __floats2half2_rn(0.f, 0.f);
  __half2 acc[GPW];
#pragma unroll
  for (int gi = 0; gi < GPW; ++gi) acc[gi] = z;

  // G % GPW == 0, so each wave's 16 g's are all-valid or all-invalid.
  if (g0w < G) {
    // Slot-major gather. ip is wave-uniform + contiguous -> s_load_dwordx16;
    // 16 independent loads in flight per slot, 16 fp16 acc chains.
#pragma unroll 2
    for (int k = 0; k < K; ++k) {
      const int* ip = sortedT + (size_t)k * Gpad + g0w;    // uniform pointer
#pragma unroll
      for (int gi = 0; gi < GPW; ++gi) {
        const int j = ip[gi];                              // SGPR via s_load
        acc[gi] = __hadd2(acc[gi], packed[(size_t)j * 64 + lane]);
      }
    }

    // Stage X: message (cols 0..63) + residual row (cols 64..127).
    const int e2 = 2 * (lane & 31);
    const int rb = (lane >> 5) * 64;                       // batch row base
#pragma unroll
    for (int gi = 0; gi < GPW; ++gi) {
      const int row = rb + w * GPW + gi;
      *(__half2*)&X[row * XS + e2] = acc[gi];
      *(__half2*)&X[row * XS + A + e2] = packed[(size_t)(g0w + gi) * 64 + lane];
    }
  }
  __syncthreads();

  // Epilogue: Y[128x64] = X[128x128] @ Wcat; tiles t = w and w+4.
  // A-frag A[m=lane&15][k=quad*8+j]; B-frag B[k=quad*8+j][n=lane&15];
  // C/D: col=lane&15, row=quad*4+reg. (Verified in R4/R6/R7.)
  const int quad = lane >> 4, mn = lane & 15;
#pragma unroll
  for (int jt = 0; jt < 2; ++jt) {
    const int t = w + 4 * jt;
    f32x4 ac[4] = {{0.f, 0.f, 0.f, 0.f}, {0.f, 0.f, 0.f, 0.f},
                   {0.f, 0.f, 0.f, 0.f}, {0.f, 0.f, 0.f, 0.f}};
#pragma unroll
    for (int kt = 0; kt < 4; ++kt) {
      const int ko = kt * 32 + quad * 8;
      const f16x8 a = *(const f16x8*)&X[(t * 16 + mn) * XS + ko];
#pragma unroll
      for (int nt = 0; nt < 4; ++nt) {
        const f16x8 bfr = *(const f16x8*)&WTg[(nt * 16 + mn) * 128 + ko];
        ac[nt] = __builtin_amdgcn_mfma_f32_16x16x32_f16(a, bfr, ac[nt], 0, 0, 0);
      }
    }
#pragma unroll
    for (int nt = 0; nt < 4; ++nt) {
      const int col = nt * 16 + mn;
      const float bv = bb[col];
#pragma unroll
      for (int rg = 0; rg < 4; ++rg) {
        const int r = quad * 4 + rg;               // row within tile
        const int bt = t >> 2;                     // batch
        const int g = blockIdx.x * GPB + (t & 3) * 16 + r;
        if (g < G) y[((size_t)bt * G + g) * 64 + col] = ac[nt][rg] + bv;
      }
    }
  }
}

extern "C" void kernel_launch(void* const* d_in, const int* in_sizes, int n_in,
                              void* d_out, int out_size, void* d_ws, size_t ws_size,
                              hipStream_t stream) {
  const float* out = (const float*)d_in[0];
  const int*   nbr = (const int*)d_in[1];
  const float* W2  = (const float*)d_in[2];
  const float* b2  = (const float*)d_in[3];
  const float* W3  = (const float*)d_in[4];
  const float* b3  = (const float*)d_in[5];
  float* y = (float*)d_out;
  const int G = in_sizes[1] / K;
  const int Gpad = (G + 63) & ~63;   // 64-aligned rows for aligned s_loads

  // ws: packed (G+1)*64 half2 | sortedT K*Gpad int | WTg 128*64 half | bb 64 f32
  __half2* packed = (__half2*)d_ws;
  const size_t pbytes = (size_t)(G + 1) * 64 * sizeof(__half2);
  int* sortedT = (int*)((char*)d_ws + pbytes);
  __half* WTg = (__half*)((char*)sortedT + (size_t)K * Gpad * sizeof(int));
  float* bbp = (float*)(WTg + 128 * 64);

  const int nPrep = ((G + 1) * 64 + 255) / 256;
  prep_kernel<<<nPrep, 256, 0, stream>>>((const float2*)out, nbr, W2, b2, W3, b3,
                                         packed, sortedT, WTg, bbp, G, Gpad, nPrep);

  const int blocks = (G + GPB - 1) / GPB;
  fused_kernel<<<blocks, 256, 0, stream>>>(packed, sortedT, WTg, bbp, y, G, Gpad);
}